// Round 7
// baseline (113.015 us; speedup 1.0000x reference)
//
#include <hip/hip_runtime.h>

#define NB 32
#define LL 4096
#define EMB 512
#define DK 256
#define DV 512
#define VOC 32768
#define EPS_ 1e-6f

typedef short bf16x8 __attribute__((ext_vector_type(8)));
typedef float f32x4 __attribute__((ext_vector_type(4)));

__device__ __forceinline__ unsigned short f2bf(float f){
    unsigned int u = __float_as_uint(f);
    return (unsigned short)((u + 0x7FFFu + ((u >> 16) & 1u)) >> 16);
}
__device__ __forceinline__ float phi_(float x){ return x > 0.f ? x + 1.f : __expf(x); }

// ---------------- kprep: {Wk -> blocked bf16 WkT2 [kt][n][32]} + {Q proj} ----------------
__global__ void kprep(const float* __restrict__ Wk_w, unsigned short* __restrict__ WkT2,
                      const int* __restrict__ q, const float* __restrict__ emb,
                      const float* __restrict__ Wq_w, const float* __restrict__ Wq_b,
                      unsigned short* __restrict__ Qbf){
    int t = threadIdx.x;
    if(blockIdx.x < 16){
        int kt = blockIdx.x, n = t;
        unsigned int w[16];
#pragma unroll
        for(int i = 0; i < 16; i++){
            float a = Wk_w[(kt*32 + 2*i    )*DK + n];
            float b = Wk_w[(kt*32 + 2*i + 1)*DK + n];
            w[i] = (unsigned int)f2bf(a) | ((unsigned int)f2bf(b) << 16);
        }
        uint4* dst = (uint4*)(WkT2 + (size_t)(kt*256 + n)*32);
#pragma unroll
        for(int qd = 0; qd < 4; qd++)
            dst[qd] = make_uint4(w[qd*4], w[qd*4+1], w[qd*4+2], w[qd*4+3]);
    } else {
        __shared__ float qe[EMB];
        int b = blockIdx.x - 16;
        int row = q[b];
        qe[t]       = emb[(size_t)row*EMB + t];
        qe[t + 256] = emb[(size_t)row*EMB + t + 256];
        __syncthreads();
        float acc = Wq_b[t];
#pragma unroll 16
        for(int e = 0; e < EMB; e++) acc += qe[e] * Wq_w[e*DK + t];
        Qbf[b*DK + t] = f2bf(phi_(acc));
    }
}

// ---------------- k2: T[vocab][b] = phi(emb_table @ Wk + bk) @ Q^T  (pipelined MFMA) ----------------
#define AST 40    // stage-1 A LDS row stride (u16), 80 B
#define PST 268   // phi LDS row stride (u16)
__launch_bounds__(512, 1)
__global__ void k2_gemm(const float* __restrict__ A, const unsigned short* __restrict__ WkT2,
                        const float* __restrict__ bias, const unsigned short* __restrict__ Qbf,
                        float* __restrict__ Tt){
    __shared__ unsigned short As[2][128*AST];   // 20480 B
    __shared__ unsigned short PhiT[64*PST];     // 34304 B   (total 54784 B)
    int tid = threadIdx.x;
    int m0 = blockIdx.x * 128;
    int wv = tid >> 6, l = tid & 63;
    int lr = l & 15, kg = l >> 4;
    int wr = wv >> 2, wc = wv & 3;

    f32x4 acc[4][4];
#pragma unroll
    for(int i = 0; i < 4; i++)
#pragma unroll
        for(int j = 0; j < 4; j++){ f32x4 z = {0.f,0.f,0.f,0.f}; acc[i][j] = z; }

    int arow = tid >> 2, aq = tid & 3;
    const float* Ap = A + (size_t)(m0 + arow) * EMB + aq*8;

    float4 rA[2], rB[2];
    bf16x8 bfr[2][4];

    rA[0] = *(const float4*)(Ap);      rB[0] = *(const float4*)(Ap + 4);
    rA[1] = *(const float4*)(Ap + 32); rB[1] = *(const float4*)(Ap + 36);
    {
        unsigned int w0 = (unsigned int)f2bf(rA[0].x) | ((unsigned int)f2bf(rA[0].y) << 16);
        unsigned int w1 = (unsigned int)f2bf(rA[0].z) | ((unsigned int)f2bf(rA[0].w) << 16);
        unsigned int w2 = (unsigned int)f2bf(rB[0].x) | ((unsigned int)f2bf(rB[0].y) << 16);
        unsigned int w3 = (unsigned int)f2bf(rB[0].z) | ((unsigned int)f2bf(rB[0].w) << 16);
        *(uint4*)(As[0] + arow*AST + aq*8) = make_uint4(w0, w1, w2, w3);
    }
#pragma unroll
    for(int fj = 0; fj < 4; fj++)
        bfr[0][fj] = *(const bf16x8*)(WkT2 + ((size_t)(wc*64 + fj*16 + lr))*32 + kg*8);
    __syncthreads();

#pragma unroll
    for(int kt = 0; kt < 16; kt++){
        const int cur = kt & 1, nxt = cur ^ 1;
        if(kt < 14){
            rA[cur] = *(const float4*)(Ap + (kt+2)*32);
            rB[cur] = *(const float4*)(Ap + (kt+2)*32 + 4);
        }
        if(kt < 15){
            unsigned int w0 = (unsigned int)f2bf(rA[nxt].x) | ((unsigned int)f2bf(rA[nxt].y) << 16);
            unsigned int w1 = (unsigned int)f2bf(rA[nxt].z) | ((unsigned int)f2bf(rA[nxt].w) << 16);
            unsigned int w2 = (unsigned int)f2bf(rB[nxt].x) | ((unsigned int)f2bf(rB[nxt].y) << 16);
            unsigned int w3 = (unsigned int)f2bf(rB[nxt].z) | ((unsigned int)f2bf(rB[nxt].w) << 16);
            *(uint4*)(As[nxt] + arow*AST + aq*8) = make_uint4(w0, w1, w2, w3);
#pragma unroll
            for(int fj = 0; fj < 4; fj++)
                bfr[nxt][fj] = *(const bf16x8*)(WkT2 + ((size_t)((kt+1)*256) + wc*64 + fj*16 + lr)*32 + kg*8);
        }
        bf16x8 af[4];
#pragma unroll
        for(int fi = 0; fi < 4; fi++)
            af[fi] = *(const bf16x8*)(As[cur] + (wr*64 + fi*16 + lr)*AST + kg*8);
#pragma unroll
        for(int fi = 0; fi < 4; fi++)
#pragma unroll
            for(int fj = 0; fj < 4; fj++)
                acc[fi][fj] = __builtin_amdgcn_mfma_f32_16x16x32_bf16(af[fi], bfr[cur][fj], acc[fi][fj], 0, 0, 0);
        __syncthreads();
    }

    // ---- epilogue: two 64-row passes. D map (verified): col=lane&15, row=(lane>>4)*4+reg ----
#pragma unroll
    for(int p = 0; p < 2; p++){
        if(wr == p){
#pragma unroll
            for(int fj = 0; fj < 4; fj++){
                int n = wc*64 + fj*16 + lr;
                float bv = bias[n];
#pragma unroll
                for(int fi = 0; fi < 4; fi++){
                    int rl = fi*16 + kg*4;
#pragma unroll
                    for(int reg = 0; reg < 4; reg++)
                        PhiT[(rl + reg)*PST + n] = f2bf(phi_(acc[fi][fj][reg] + bv));
                }
            }
        }
        __syncthreads();
        {
            int m = wv & 1, rt = wv >> 1;   // 8 waves = 2 m-tiles x 4 r-tiles
            f32x4 acc2 = {0.f,0.f,0.f,0.f};
#pragma unroll
            for(int kt2 = 0; kt2 < 8; kt2++){
                bf16x8 aq2 = *(const bf16x8*)(Qbf + (m*16 + lr)*DK + kt2*32 + kg*8);
                bf16x8 bp  = *(const bf16x8*)(PhiT + (rt*16 + lr)*PST + kt2*32 + kg*8);
                acc2 = __builtin_amdgcn_mfma_f32_16x16x32_bf16(aq2, bp, acc2, 0, 0, 0);
            }
            int vrow = m0 + p*64 + rt*16 + lr;
            int bcol = m*16 + kg*4;
            *(f32x4*)(Tt + (size_t)vrow*32 + bcol) = acc2;
        }
        __syncthreads();
    }
}

// ---------------- k3: issue-early gather + 8-deep pipelined V-stream ----------------
// grid: 1024 blocks = (b=bx>>5, chunk=bx&31), 256 threads, 128 tokens/block
// V loads are PLAIN (cacheable) so L3 retains V across graph replays; pnum store stays NT.
__global__ void k3_fused(const int* __restrict__ kk_, const float* __restrict__ V,
                         const float* __restrict__ Tt,
                         float* __restrict__ pnum, float* __restrict__ pden){
    __shared__ float s_l[128];
    int t = threadIdx.x;
    int b = blockIdx.x >> 5, ch = blockIdx.x & 31;

    int half = t >> 7, c4 = t & 127;
    const float* vbase = V + (size_t)(b*LL + ch*128) * DV;

    // issue s-gather early
    float sv = 0.f;
    if(t < 128){
        int row = kk_[b*LL + ch*128 + t];
        sv = Tt[(size_t)row*32 + b];
    }
    // prefetch first 8 V vectors (independent of s) before the barrier
    f32x4 vp[8];
#pragma unroll
    for(int i = 0; i < 8; i++)
        vp[i] = *(const f32x4*)(vbase + (size_t)(2*i + half)*DV + c4*4);

    if(t < 128) s_l[t] = sv;
    __syncthreads();

    // den partial (wave 0; other waves proceed)
    if(t < 64){
        float d = s_l[t] + s_l[t+64];
#pragma unroll
        for(int off = 32; off; off >>= 1) d += __shfl_down(d, off);
        if(t == 0) pden[ch*32 + b] = d;
    }

    float ax0=0.f, ay0=0.f, az0=0.f, aw0=0.f;
    float ax1=0.f, ay1=0.f, az1=0.f, aw1=0.f;
    for(int base = 0; base < 64; base += 8){
        f32x4 vn[8];
#pragma unroll
        for(int i = 0; i < 8; i++) vn[i] = vp[i];
        if(base + 8 < 64){
#pragma unroll
            for(int i = 0; i < 8; i++)
                vn[i] = *(const f32x4*)(vbase + (size_t)(2*(base+8+i) + half)*DV + c4*4);
        }
#pragma unroll
        for(int i = 0; i < 8; i++){
            float s = s_l[2*(base+i) + half];
            if(i & 1){ ax1 += s*vp[i][0]; ay1 += s*vp[i][1]; az1 += s*vp[i][2]; aw1 += s*vp[i][3]; }
            else     { ax0 += s*vp[i][0]; ay0 += s*vp[i][1]; az0 += s*vp[i][2]; aw0 += s*vp[i][3]; }
        }
#pragma unroll
        for(int i = 0; i < 8; i++) vp[i] = vn[i];
    }
    f32x4 res = {ax0+ax1, ay0+ay1, az0+az1, aw0+aw1};
    __builtin_nontemporal_store(res, (f32x4*)(pnum + (size_t)((ch*2 + half)*32 + b)*DV + c4*4));
}

// ---------------- k4: finalize (grid 256, block 64) ----------------
__global__ void k4_final(const float* __restrict__ pnum, const float* __restrict__ pden,
                         float* __restrict__ out){
    int b = blockIdx.x >> 3, vg = blockIdx.x & 7;
    int t = threadIdx.x;
    float d = 0.f;
#pragma unroll
    for(int ch = 0; ch < 32; ch++) d += pden[ch*32 + b];
    d += EPS_;
    int v = vg*64 + t;
    float num = 0.f;
#pragma unroll
    for(int s = 0; s < 64; s++) num += pnum[(size_t)(s*32 + b)*DV + v];
    out[b*DV + v] = num / d;
}

extern "C" void kernel_launch(void* const* d_in, const int* in_sizes, int n_in,
                              void* d_out, int out_size, void* d_ws, size_t ws_size,
                              hipStream_t stream) {
    const int*   k_    = (const int*)d_in[0];
    const int*   q_    = (const int*)d_in[1];
    const float* v_emb = (const float*)d_in[2];
    const float* emb   = (const float*)d_in[3];
    const float* Wk_w  = (const float*)d_in[4];
    const float* Wk_b  = (const float*)d_in[5];
    const float* Wq_w  = (const float*)d_in[6];
    const float* Wq_b  = (const float*)d_in[7];
    float* out = (float*)d_out;

    char* ws = (char*)d_ws;
    unsigned short* WkT2 = (unsigned short*)(ws);                 //   262144 B
    unsigned short* Qbf  = (unsigned short*)(ws + 262144);        //    16384 B
    float* Tt            = (float*)(ws + 278528);                 //  4194304 B  [VOC][32]
    float* pnum          = (float*)(ws + 4472832);                //  4194304 B
    float* pden          = (float*)(ws + 8667136);                //     4096 B
    // total ws usage: 8,671,232 B

    kprep  <<<48,   256, 0, stream>>>(Wk_w, WkT2, q_, emb, Wq_w, Wq_b, Qbf);
    k2_gemm<<<256,  512, 0, stream>>>(emb, WkT2, Wk_b, Qbf, Tt);
    k3_fused<<<1024,256, 0, stream>>>(k_, v_emb, Tt, pnum, pden);
    k4_final<<<256,  64, 0, stream>>>(pnum, pden, out);
}

// Round 8
// 84.490 us; speedup vs baseline: 1.3376x; 1.3376x over previous
//
#include <hip/hip_runtime.h>

#define NB 32
#define LL 4096
#define EMB 512
#define DK 256
#define DV 512
#define VOC 32768
#define EPS_ 1e-6f

typedef short bf16x8 __attribute__((ext_vector_type(8)));
typedef float f32x4 __attribute__((ext_vector_type(4)));

__device__ __forceinline__ unsigned short f2bf(float f){
    unsigned int u = __float_as_uint(f);
    return (unsigned short)((u + 0x7FFFu + ((u >> 16) & 1u)) >> 16);
}
__device__ __forceinline__ float phi_(float x){ return x > 0.f ? x + 1.f : __expf(x); }

// ---------------- kprep: {Wk -> blocked bf16 WkT2 [kt][n][32]} + {Q proj} ----------------
__global__ void kprep(const float* __restrict__ Wk_w, unsigned short* __restrict__ WkT2,
                      const int* __restrict__ q, const float* __restrict__ emb,
                      const float* __restrict__ Wq_w, const float* __restrict__ Wq_b,
                      unsigned short* __restrict__ Qbf){
    int t = threadIdx.x;
    if(blockIdx.x < 16){
        int kt = blockIdx.x, n = t;
        unsigned int w[16];
#pragma unroll
        for(int i = 0; i < 16; i++){
            float a = Wk_w[(kt*32 + 2*i    )*DK + n];
            float b = Wk_w[(kt*32 + 2*i + 1)*DK + n];
            w[i] = (unsigned int)f2bf(a) | ((unsigned int)f2bf(b) << 16);
        }
        uint4* dst = (uint4*)(WkT2 + (size_t)(kt*256 + n)*32);
#pragma unroll
        for(int qd = 0; qd < 4; qd++)
            dst[qd] = make_uint4(w[qd*4], w[qd*4+1], w[qd*4+2], w[qd*4+3]);
    } else {
        __shared__ float qe[EMB];
        int b = blockIdx.x - 16;
        int row = q[b];
        qe[t]       = emb[(size_t)row*EMB + t];
        qe[t + 256] = emb[(size_t)row*EMB + t + 256];
        __syncthreads();
        float acc = Wq_b[t];
#pragma unroll 16
        for(int e = 0; e < EMB; e++) acc += qe[e] * Wq_w[e*DK + t];
        Qbf[b*DK + t] = f2bf(phi_(acc));
    }
}

// ---------------- k2: T[vocab][b] = phi(emb_table @ Wk + bk) @ Q^T ----------------
// BM=64, 256 thr (4 waves, each 64 rows x 64 cols), grid 512 -> 2 blocks/CU resident, 3 max.
// A: depth-2 register staging -> double-buffered LDS. B: register ping-pong from blocked WkT2 (L2).
// Epilogue: PhiT union-aliases the dead As buffer (LDS = 34304 B); single pass; 2 T-GEMM tasks/wave.
#define AST 40    // A LDS row stride (u16), 80 B
#define PST 268   // phi LDS row stride (u16)
__launch_bounds__(256, 3)
__global__ void k2_gemm(const float* __restrict__ A, const unsigned short* __restrict__ WkT2,
                        const float* __restrict__ bias, const unsigned short* __restrict__ Qbf,
                        float* __restrict__ Tt){
    __shared__ unsigned short sh[64*PST];       // 34304 B; aliases As(2x64xAST=10240 u16) and PhiT
    unsigned short* As0  = sh;
    unsigned short* As1  = sh + 64*AST;
    unsigned short* PhiT = sh;
    int tid = threadIdx.x;
    int m0 = blockIdx.x * 64;
    int wv = tid >> 6, l = tid & 63;
    int lr = l & 15, kg = l >> 4;
    int wc = wv;                                // 4 waves = 4 col-tiles of 64

    f32x4 acc[4][4];
#pragma unroll
    for(int i = 0; i < 4; i++)
#pragma unroll
        for(int j = 0; j < 4; j++){ f32x4 z = {0.f,0.f,0.f,0.f}; acc[i][j] = z; }

    int arow = tid >> 2, aq = tid & 3;          // 64 rows x 4 thr x 8 floats
    const float* Ap = A + (size_t)(m0 + arow) * EMB + aq*8;

    float4 rA[2], rB[2];
    bf16x8 bfr[2][4];

    rA[0] = *(const float4*)(Ap);      rB[0] = *(const float4*)(Ap + 4);
    rA[1] = *(const float4*)(Ap + 32); rB[1] = *(const float4*)(Ap + 36);
    {
        unsigned int w0 = (unsigned int)f2bf(rA[0].x) | ((unsigned int)f2bf(rA[0].y) << 16);
        unsigned int w1 = (unsigned int)f2bf(rA[0].z) | ((unsigned int)f2bf(rA[0].w) << 16);
        unsigned int w2 = (unsigned int)f2bf(rB[0].x) | ((unsigned int)f2bf(rB[0].y) << 16);
        unsigned int w3 = (unsigned int)f2bf(rB[0].z) | ((unsigned int)f2bf(rB[0].w) << 16);
        *(uint4*)(As0 + arow*AST + aq*8) = make_uint4(w0, w1, w2, w3);
    }
#pragma unroll
    for(int fj = 0; fj < 4; fj++)
        bfr[0][fj] = *(const bf16x8*)(WkT2 + ((size_t)(wc*64 + fj*16 + lr))*32 + kg*8);
    __syncthreads();

#pragma unroll
    for(int kt = 0; kt < 16; kt++){
        const int cur = kt & 1, nxt = cur ^ 1;
        unsigned short* Acur = cur ? As1 : As0;
        unsigned short* Anxt = cur ? As0 : As1;
        if(kt < 14){
            rA[cur] = *(const float4*)(Ap + (kt+2)*32);
            rB[cur] = *(const float4*)(Ap + (kt+2)*32 + 4);
        }
        if(kt < 15){
            unsigned int w0 = (unsigned int)f2bf(rA[nxt].x) | ((unsigned int)f2bf(rA[nxt].y) << 16);
            unsigned int w1 = (unsigned int)f2bf(rA[nxt].z) | ((unsigned int)f2bf(rA[nxt].w) << 16);
            unsigned int w2 = (unsigned int)f2bf(rB[nxt].x) | ((unsigned int)f2bf(rB[nxt].y) << 16);
            unsigned int w3 = (unsigned int)f2bf(rB[nxt].z) | ((unsigned int)f2bf(rB[nxt].w) << 16);
            *(uint4*)(Anxt + arow*AST + aq*8) = make_uint4(w0, w1, w2, w3);
#pragma unroll
            for(int fj = 0; fj < 4; fj++)
                bfr[nxt][fj] = *(const bf16x8*)(WkT2 + ((size_t)((kt+1)*256) + wc*64 + fj*16 + lr)*32 + kg*8);
        }
        bf16x8 af[4];
#pragma unroll
        for(int fi = 0; fi < 4; fi++)
            af[fi] = *(const bf16x8*)(Acur + (fi*16 + lr)*AST + kg*8);
#pragma unroll
        for(int fi = 0; fi < 4; fi++)
#pragma unroll
            for(int fj = 0; fj < 4; fj++)
                acc[fi][fj] = __builtin_amdgcn_mfma_f32_16x16x32_bf16(af[fi], bfr[cur][fj], acc[fi][fj], 0, 0, 0);
        __syncthreads();
    }

    // ---- epilogue (single pass). D map (verified): col=lane&15, row=(lane>>4)*4+reg ----
#pragma unroll
    for(int fj = 0; fj < 4; fj++){
        int n = wc*64 + fj*16 + lr;
        float bv = bias[n];
#pragma unroll
        for(int fi = 0; fi < 4; fi++){
            int rl = fi*16 + kg*4;
#pragma unroll
            for(int reg = 0; reg < 4; reg++)
                PhiT[(rl + reg)*PST + n] = f2bf(phi_(acc[fi][fj][reg] + bv));
        }
    }
    __syncthreads();
    // T-GEMM: A = Q (M=32 b), B = PhiT (N=64 rows), K=256; 8 tasks over 4 waves
#pragma unroll
    for(int task = 0; task < 2; task++){
        int id = wv*2 + task;
        int m = id & 1, rt = id >> 1;           // m: 2 batch-tiles, rt: 4 row-tiles
        f32x4 acc2 = {0.f,0.f,0.f,0.f};
#pragma unroll
        for(int kt2 = 0; kt2 < 8; kt2++){
            bf16x8 aq2 = *(const bf16x8*)(Qbf + (m*16 + lr)*DK + kt2*32 + kg*8);
            bf16x8 bp  = *(const bf16x8*)(PhiT + (rt*16 + lr)*PST + kt2*32 + kg*8);
            acc2 = __builtin_amdgcn_mfma_f32_16x16x32_bf16(aq2, bp, acc2, 0, 0, 0);
        }
        int vrow = m0 + rt*16 + lr;             // N-dim = vocab row (col=lane&15)
        int bcol = m*16 + kg*4;                 // M-dim = batch (row=(lane>>4)*4+reg)
        *(f32x4*)(Tt + (size_t)vrow*32 + bcol) = acc2;
    }
}

// ---------------- k3: scalar-gather s + V-stream (round-4 known-good body, FROZEN) ----------------
// grid: 1024 blocks = (b=bx>>5, chunk=bx&31), 256 threads, 128 tokens/block
__global__ void k3_fused(const int* __restrict__ kk_, const float* __restrict__ V,
                         const float* __restrict__ Tt,
                         float* __restrict__ pnum, float* __restrict__ pden){
    __shared__ float s_l[128];
    int t = threadIdx.x;
    int b = blockIdx.x >> 5, ch = blockIdx.x & 31;

    if(t < 128){
        int row = kk_[b*LL + ch*128 + t];
        s_l[t] = Tt[(size_t)row*32 + b];
    }
    __syncthreads();

    // den partial (wave 0)
    if(t < 64){
        float d = s_l[t] + s_l[t+64];
#pragma unroll
        for(int off = 32; off; off >>= 1) d += __shfl_down(d, off);
        if(t == 0) pden[ch*32 + b] = d;
    }

    // num partials: 128 lanes per token (float4), 2 tokens interleaved, nontemporal V
    int half = t >> 7, c4 = t & 127;
    const float* vbase = V + (size_t)(b*LL + ch*128) * DV;
    float ax = 0.f, ay = 0.f, az = 0.f, aw = 0.f;
#pragma unroll 4
    for(int i = 0; i < 64; i++){
        int lp = 2*i + half;
        float s = s_l[lp];
        f32x4 v = __builtin_nontemporal_load((const f32x4*)(vbase + (size_t)lp*DV + c4*4));
        ax += s*v[0]; ay += s*v[1]; az += s*v[2]; aw += s*v[3];
    }
    f32x4 res = {ax, ay, az, aw};
    __builtin_nontemporal_store(res, (f32x4*)(pnum + (size_t)((ch*2 + half)*32 + b)*DV + c4*4));
}

// ---------------- k4: finalize (grid 256, block 64) ----------------
__global__ void k4_final(const float* __restrict__ pnum, const float* __restrict__ pden,
                         float* __restrict__ out){
    int b = blockIdx.x >> 3, vg = blockIdx.x & 7;
    int t = threadIdx.x;
    float d = 0.f;
#pragma unroll
    for(int ch = 0; ch < 32; ch++) d += pden[ch*32 + b];
    d += EPS_;
    int v = vg*64 + t;
    float num = 0.f;
#pragma unroll
    for(int s = 0; s < 64; s++) num += pnum[(size_t)(s*32 + b)*DV + v];
    out[b*DV + v] = num / d;
}

extern "C" void kernel_launch(void* const* d_in, const int* in_sizes, int n_in,
                              void* d_out, int out_size, void* d_ws, size_t ws_size,
                              hipStream_t stream) {
    const int*   k_    = (const int*)d_in[0];
    const int*   q_    = (const int*)d_in[1];
    const float* v_emb = (const float*)d_in[2];
    const float* emb   = (const float*)d_in[3];
    const float* Wk_w  = (const float*)d_in[4];
    const float* Wk_b  = (const float*)d_in[5];
    const float* Wq_w  = (const float*)d_in[6];
    const float* Wq_b  = (const float*)d_in[7];
    float* out = (float*)d_out;

    char* ws = (char*)d_ws;
    unsigned short* WkT2 = (unsigned short*)(ws);                 //   262144 B
    unsigned short* Qbf  = (unsigned short*)(ws + 262144);        //    16384 B
    float* Tt            = (float*)(ws + 278528);                 //  4194304 B  [VOC][32]
    float* pnum          = (float*)(ws + 4472832);                //  4194304 B
    float* pden          = (float*)(ws + 8667136);                //     4096 B
    // total ws usage: 8,671,232 B

    kprep  <<<48,   256, 0, stream>>>(Wk_w, WkT2, q_, emb, Wq_w, Wq_b, Qbf);
    k2_gemm<<<512,  256, 0, stream>>>(emb, WkT2, Wk_b, Qbf, Tt);
    k3_fused<<<1024,256, 0, stream>>>(k_, v_emb, Tt, pnum, pden);
    k4_final<<<256,  64, 0, stream>>>(pnum, pden, out);
}